// Round 5
// baseline (353.829 us; speedup 1.0000x reference)
//
#include <hip/hip_runtime.h>

// Capsule routing, factorized, all fp32, multi-kernel (no global atomics).
// B=256, K_IN=8, C=1152, J=10, D=16, 4 iters.
// m = k*1152 + c (M=9216), n = j*16 + d (N=160).
// Per iter: [gemm1] s_part[ch][b][n] = sum_{m in ch} Xt[m,b]*csm[c,j]*Wr[m,n]
//           (gemm1 prologue: b_ij += sum_be agg_part; csm = softmax(b_ij))
//           [squash] v[b][n] = squash(sum_ch s_part)
//           [gemm2]  agg_part[be][c][j] = sum_{b in eighth,k,d} Wr[m,n]*x[b,m]*v[b,n]

#define C_IN  1152
#define J_U   10
#define M_DIM 9216
#define N_DIM 160
#define B_SZ  256

// ---- ws layout (float offsets); ws is 256 MiB so offsets are generous ----
#define OFF_XT   0                    // [9218+][256]  (2 pad rows for 2-deep prefetch)
#define OFF_WR   2400000              // [9216][160]
#define OFF_SP   3900000              // [128][256][160]
#define OFF_V    9200000              // [256][160]
#define OFF_B0   9250000              // [1152][10]
#define OFF_B1   9270000              // [1152][10]
#define OFF_AG   9290000              // [8][1152][10]

// ================= prep: transpose x -> Xt, build Wr, zero b_ij/agg =================
__global__ __launch_bounds__(256) void k_prep(const float* __restrict__ x,
                                              const float* __restrict__ W,
                                              float* __restrict__ ws) {
    const int bid = blockIdx.x, t = threadIdx.x;
    if (bid < 576) {                       // 144 m-tiles x 4 b-tiles, 64x64 transpose
        __shared__ float T[64][65];
        const int m0 = (bid % 144) * 64, b0 = (bid / 144) * 64;
        {
            const int b_l = t >> 2, q = t & 3;
            const float* xp = x + (size_t)(b0 + b_l) * M_DIM + m0 + q * 16;
#pragma unroll
            for (int u = 0; u < 4; ++u) {
                const float4 v = *reinterpret_cast<const float4*>(xp + 4 * u);
                T[q * 16 + 4 * u + 0][b_l] = v.x;
                T[q * 16 + 4 * u + 1][b_l] = v.y;
                T[q * 16 + 4 * u + 2][b_l] = v.z;
                T[q * 16 + 4 * u + 3][b_l] = v.w;
            }
        }
        __syncthreads();
        {
            const int m_l = t >> 2, q = t & 3;
            float* Xt = ws + OFF_XT;
            float4* op = reinterpret_cast<float4*>(Xt + (size_t)(m0 + m_l) * B_SZ + b0 + q * 16);
#pragma unroll
            for (int u = 0; u < 4; ++u)
                op[u] = make_float4(T[m_l][q * 16 + 4 * u], T[m_l][q * 16 + 4 * u + 1],
                                    T[m_l][q * 16 + 4 * u + 2], T[m_l][q * 16 + 4 * u + 3]);
        }
    } else if (bid < 2016) {               // Wr[(k*C+c)][n] = W[c][n][k]
        const int i = (bid - 576) * 256 + t;    // [0, 368640)
        const int n = i % N_DIM;
        const int c = (i / N_DIM) % C_IN;
        const int kh = i / (N_DIM * C_IN);      // 0..1
        const float4 w = *reinterpret_cast<const float4*>(W + (size_t)c * 1280 + n * 8 + kh * 4);
        float* Wr = ws + OFF_WR;
        const float wv[4] = {w.x, w.y, w.z, w.w};
#pragma unroll
        for (int j = 0; j < 4; ++j)
            Wr[(size_t)((kh * 4 + j) * C_IN + c) * N_DIM + n] = wv[j];
    } else {                               // zero b_ij (both buffers) + agg_part (8 slices)
        const int idx = (bid - 2016) * 256 + t;   // [0, 11520)
        ws[OFF_B0 + idx] = 0.f;
        ws[OFF_B1 + idx] = 0.f;
#pragma unroll
        for (int s = 0; s < 8; ++s) ws[OFF_AG + s * 11520 + idx] = 0.f;
    }
}

// ================= gemm1: 128 chunks(72 m) x 2 b-halves(128 b) =================
// prologue: b_ij update + softmax (duplicated x2 across bg blocks sharing a c-range).
__global__ __launch_bounds__(256, 1) void k_gemm1(const float* __restrict__ Xt,
                                                  const float4* __restrict__ Wr4,
                                                  const float* __restrict__ bij_old,
                                                  float* __restrict__ bij_new,
                                                  const float* __restrict__ agg_part,
                                                  float* __restrict__ s_part) {
    __shared__ float braw[720];
    __shared__ float csm[720];
    __shared__ float Ws[72 * 160];
    const int ch = blockIdx.x >> 1, bg = blockIdx.x & 1;
    const int m0 = ch * 72;
    const int c0 = (ch & 15) * 72;        // chunk sits inside one k-slice (1152/72=16)
    const int t = threadIdx.x;

    // ---- b_ij += sum_be agg_part ; write new buffer (same value from all dups) ----
    for (int idx = t; idx < 720; idx += 256) {
        float v = bij_old[c0 * J_U + idx];
#pragma unroll
        for (int s = 0; s < 8; ++s) v += agg_part[s * 11520 + c0 * J_U + idx];
        braw[idx] = v;
        bij_new[c0 * J_U + idx] = v;
    }
    __syncthreads();
    for (int idx = t; idx < 720; idx += 256) {    // softmax over j
        const int r0 = (idx / J_U) * J_U;
        float mx = -1e30f;
#pragma unroll
        for (int j = 0; j < J_U; ++j) mx = fmaxf(mx, braw[r0 + j]);
        float sum = 0.f;
#pragma unroll
        for (int j = 0; j < J_U; ++j) sum += __expf(braw[r0 + j] - mx);
        csm[idx] = __expf(braw[idx] - mx) / sum;
    }
    __syncthreads();
    // ---- stage scaled W panel ----
    float4* Ws4 = reinterpret_cast<float4*>(Ws);
    for (int i = t; i < 2880; i += 256) {          // 72 rows x 40 float4
        const int row = i / 40, q = i - row * 40;
        const float sc = csm[row * J_U + (q >> 2)];
        const float4 w = Wr4[(size_t)(m0 + row) * 40 + q];
        Ws4[i] = make_float4(w.x * sc, w.y * sc, w.z * sc, w.w * sc);
    }
    __syncthreads();
    // ---- main loop: x from global (2-deep prefetch), w from LDS (broadcast) ----
    const int bq = t & 15, ng = t >> 4;
    const float* xb = Xt + (size_t)m0 * B_SZ + bg * 128 + bq * 8;
    float acc[8][10] = {};
    float4 a0 = *reinterpret_cast<const float4*>(xb);
    float4 a1 = *reinterpret_cast<const float4*>(xb + 4);
    float4 b0 = *reinterpret_cast<const float4*>(xb + B_SZ);
    float4 b1 = *reinterpret_cast<const float4*>(xb + B_SZ + 4);
#pragma unroll 2
    for (int m = 0; m < 72; ++m) {
        const float* xf = xb + (size_t)(m + 2) * B_SZ;  // rows 9216..9289 hit pad (unused)
        const float4 c0v = *reinterpret_cast<const float4*>(xf);
        const float4 c1v = *reinterpret_cast<const float4*>(xf + 4);
        const float2* wr = reinterpret_cast<const float2*>(Ws + m * N_DIM + ng * J_U);
        const float xv[8] = {a0.x, a0.y, a0.z, a0.w, a1.x, a1.y, a1.z, a1.w};
#pragma unroll
        for (int jj = 0; jj < 5; ++jj) {
            const float2 wv = wr[jj];
#pragma unroll
            for (int i = 0; i < 8; ++i) {
                acc[i][2 * jj]     += xv[i] * wv.x;
                acc[i][2 * jj + 1] += xv[i] * wv.y;
            }
        }
        a0 = b0; a1 = b1; b0 = c0v; b1 = c1v;
    }
    // ---- store split-K partials (plain stores) ----
    float* sp = s_part + (size_t)ch * 40960 + (size_t)(bg * 128 + bq * 8) * N_DIM + ng * J_U;
#pragma unroll
    for (int i = 0; i < 8; ++i) {
        float2* p = reinterpret_cast<float2*>(sp + (size_t)i * N_DIM);
#pragma unroll
        for (int jj = 0; jj < 5; ++jj) p[jj] = make_float2(acc[i][2 * jj], acc[i][2 * jj + 1]);
    }
}

// ================= squash: reduce 128 slices, squash over d -> dst =================
__global__ __launch_bounds__(320) void k_squash(const float* __restrict__ s_part,
                                                float* __restrict__ dst) {
    __shared__ float red[320];
    __shared__ float sq[160];
    const int b = blockIdx.x, t = threadIdx.x;
    const int n = t % 160, h = t / 160;
    float s = 0.f;
    const float* p = s_part + (size_t)h * 64 * 40960 + (size_t)b * N_DIM + n;
#pragma unroll 8
    for (int sl = 0; sl < 64; ++sl) s += p[(size_t)sl * 40960];
    red[t] = s;
    __syncthreads();
    if (t < 160) {
        s = red[t] + red[t + 160] + 1e-5f;   // reference adds 1e-5 BEFORE magnitudes
        sq[t] = s * s;
        red[t] = s;
    }
    __syncthreads();
    if (t < 160) {
        const int j0 = t & ~15;
        float mag = 0.f;
#pragma unroll
        for (int d = 0; d < 16; ++d) mag += sq[j0 + d];
        dst[(size_t)b * N_DIM + t] = red[t] * (sqrtf(mag) / (1.f + mag));
    }
}

// ================= gemm2: 72 c-tiles(16 c, all 8 k) x 8 b-eighths(32 b) =================
// agg_part[be][c][j] = sum_{b in eighth} sum_{k,d} Wr[m,n]*x[b,m]*v[b,n]  (plain stores)
__global__ __launch_bounds__(256, 2) void k_gemm2(const float* __restrict__ x,
                                                  const float* __restrict__ v,
                                                  const float* __restrict__ Wr,
                                                  float* __restrict__ agg_part) {
    __shared__ float Vs[32 * 160];
    __shared__ float agg[160];
    const int c0 = (blockIdx.x >> 3) * 16, be = blockIdx.x & 7;
    const int t = threadIdx.x;
    const int tm = t & 15, ng = t >> 4;
    const int kp = tm >> 2;               // k-pair: k = 2*kp, 2*kp+1
    const int csub = (tm & 3) * 4;        // 4 consecutive c
    // stage v eighth
    float4* Vs4 = reinterpret_cast<float4*>(Vs);
    const float4* v4 = reinterpret_cast<const float4*>(v);
    for (int i = t; i < 1280; i += 256) Vs4[i] = v4[(size_t)be * 1280 + i];
    if (t < 160) agg[t] = 0.f;
    __syncthreads();

    float acc[8][10] = {};
    const float* xbase = x + (size_t)be * 32 * M_DIM + c0 + csub;
    const size_t krow0 = (size_t)(2 * kp) * C_IN, krow1 = (size_t)(2 * kp + 1) * C_IN;
    float4 p0 = *reinterpret_cast<const float4*>(xbase + krow0);
    float4 p1 = *reinterpret_cast<const float4*>(xbase + krow1);
#pragma unroll 2
    for (int b = 0; b < 32; ++b) {
        const float* xr = xbase + (size_t)((b + 1) & 31) * M_DIM;  // wrap: stays in-bounds
        const float4 f0 = *reinterpret_cast<const float4*>(xr + krow0);
        const float4 f1 = *reinterpret_cast<const float4*>(xr + krow1);
        const float2* vv = reinterpret_cast<const float2*>(Vs + b * N_DIM + ng * J_U);
        const float xv[8] = {p0.x, p0.y, p0.z, p0.w, p1.x, p1.y, p1.z, p1.w};
#pragma unroll
        for (int jj = 0; jj < 5; ++jj) {
            const float2 w = vv[jj];
#pragma unroll
            for (int r = 0; r < 8; ++r) {
                acc[r][2 * jj]     += xv[r] * w.x;
                acc[r][2 * jj + 1] += xv[r] * w.y;
            }
        }
        p0 = f0; p1 = f1;
    }
    // fold with Wr (global, L2/L3-hot), k-reduce in-thread, c/j-reduce via LDS atomics
#pragma unroll
    for (int r = 0; r < 8; ++r) {
        const int kk = r >> 2, cc = r & 3;
        const size_t m = (size_t)(2 * kp + kk) * C_IN + c0 + csub + cc;
        const float* wrow = Wr + m * N_DIM + ng * J_U;
        float psum = 0.f;
        int curj = (ng * J_U) >> 4;
#pragma unroll
        for (int jj = 0; jj < 10; ++jj) {
            const int j = (ng * J_U + jj) >> 4;
            if (j != curj) {
                atomicAdd(&agg[(csub + cc) * J_U + curj], psum);
                psum = 0.f;
                curj = j;
            }
            psum += acc[r][jj] * wrow[jj];
        }
        atomicAdd(&agg[(csub + cc) * J_U + curj], psum);
    }
    __syncthreads();
    if (t < 160) agg_part[(size_t)be * 11520 + c0 * J_U + t] = agg[t];
}

extern "C" void kernel_launch(void* const* d_in, const int* in_sizes, int n_in,
                              void* d_out, int out_size, void* d_ws, size_t ws_size,
                              hipStream_t stream) {
    const float* x = (const float*)d_in[0];   // (256, 8, 1152) fp32
    const float* W = (const float*)d_in[1];   // (1, 1152, 10, 16, 8) fp32
    float* out = (float*)d_out;               // (256, 10, 16, 1) fp32
    float* ws  = (float*)d_ws;
    float* Xt   = ws + OFF_XT;
    float* Wr   = ws + OFF_WR;
    float* sp   = ws + OFF_SP;
    float* v    = ws + OFF_V;
    float* bij0 = ws + OFF_B0;
    float* bij1 = ws + OFF_B1;
    float* agg  = ws + OFF_AG;
    const float4* Wr4 = (const float4*)Wr;

    k_prep<<<2061, 256, 0, stream>>>(x, W, ws);

    for (int it = 0; it < 4; ++it) {
        const float* bo = (it & 1) ? bij1 : bij0;
        float*       bn = (it & 1) ? bij0 : bij1;
        k_gemm1<<<256, 256, 0, stream>>>(Xt, Wr4, bo, bn, agg, sp);
        k_squash<<<256, 320, 0, stream>>>(sp, (it < 3) ? v : out);
        if (it < 3)   // last iteration's agreement is never used
            k_gemm2<<<576, 256, 0, stream>>>(x, v, Wr, agg);
    }
}

// Round 6
// 305.174 us; speedup vs baseline: 1.1594x; 1.1594x over previous
//
#include <hip/hip_runtime.h>

// Capsule routing, factorized, all fp32, multi-kernel (no global atomics).
// B=256, K_IN=8, C=1152, J=10, D=16, 4 iters.
// m = k*1152 + c (M=9216), n = j*16 + d (N=160).
// Per iter: [gemm1] s_part[ch][b][n] = sum_{m in ch} Xt[m,b]*csm[c,j]*Wr[m,n]
//           (gemm1 prologue: b_ij += sum_32 agg_part; csm = softmax(b_ij))
//           [squash] v[b][n] = squash(sum_ch s_part)
//           [gemm2]  G-tile = sum_{b in quarter} x[b,m]*v[b,n] (regs, coalesced x)
//                    then fold with Wr (coalesced, LDS round-trip) -> agg_part[bq*8+k]

#define C_IN  1152
#define J_U   10
#define M_DIM 9216
#define N_DIM 160
#define B_SZ  256

// ---- ws layout (float offsets); ws is 256 MiB so offsets are generous ----
#define OFF_XT   0                    // [9218+][256]  (2 pad rows for 2-deep prefetch)
#define OFF_WR   2400000              // [9216][160]
#define OFF_SP   3900000              // [128][256][160]
#define OFF_V    9200000              // [256][160]
#define OFF_B0   9250000              // [1152][10]
#define OFF_B1   9270000              // [1152][10]
#define OFF_AG   9290000              // [32][1152][10]

// ================= prep: transpose x -> Xt, build Wr, zero b_ij/agg =================
__global__ __launch_bounds__(256) void k_prep(const float* __restrict__ x,
                                              const float* __restrict__ W,
                                              float* __restrict__ ws) {
    const int bid = blockIdx.x, t = threadIdx.x;
    if (bid < 576) {                       // 144 m-tiles x 4 b-tiles, 64x64 transpose
        __shared__ float T[64][65];
        const int m0 = (bid % 144) * 64, b0 = (bid / 144) * 64;
        {
            const int b_l = t >> 2, q = t & 3;
            const float* xp = x + (size_t)(b0 + b_l) * M_DIM + m0 + q * 16;
#pragma unroll
            for (int u = 0; u < 4; ++u) {
                const float4 v = *reinterpret_cast<const float4*>(xp + 4 * u);
                T[q * 16 + 4 * u + 0][b_l] = v.x;
                T[q * 16 + 4 * u + 1][b_l] = v.y;
                T[q * 16 + 4 * u + 2][b_l] = v.z;
                T[q * 16 + 4 * u + 3][b_l] = v.w;
            }
        }
        __syncthreads();
        {
            const int m_l = t >> 2, q = t & 3;
            float* Xt = ws + OFF_XT;
            float4* op = reinterpret_cast<float4*>(Xt + (size_t)(m0 + m_l) * B_SZ + b0 + q * 16);
#pragma unroll
            for (int u = 0; u < 4; ++u)
                op[u] = make_float4(T[m_l][q * 16 + 4 * u], T[m_l][q * 16 + 4 * u + 1],
                                    T[m_l][q * 16 + 4 * u + 2], T[m_l][q * 16 + 4 * u + 3]);
        }
    } else if (bid < 2016) {               // Wr[(k*C+c)][n] = W[c][n][k]
        const int i = (bid - 576) * 256 + t;    // [0, 368640)
        const int n = i % N_DIM;
        const int c = (i / N_DIM) % C_IN;
        const int kh = i / (N_DIM * C_IN);      // 0..1
        const float4 w = *reinterpret_cast<const float4*>(W + (size_t)c * 1280 + n * 8 + kh * 4);
        float* Wr = ws + OFF_WR;
        const float wv[4] = {w.x, w.y, w.z, w.w};
#pragma unroll
        for (int j = 0; j < 4; ++j)
            Wr[(size_t)((kh * 4 + j) * C_IN + c) * N_DIM + n] = wv[j];
    } else {                               // zero b_ij (both buffers) + agg_part (32 slices)
        const int idx = (bid - 2016) * 256 + t;   // [0, 11520)
        ws[OFF_B0 + idx] = 0.f;
        ws[OFF_B1 + idx] = 0.f;
#pragma unroll
        for (int s = 0; s < 32; ++s) ws[OFF_AG + s * 11520 + idx] = 0.f;
    }
}

// ================= gemm1: 128 chunks(72 m) x 2 b-halves(128 b) =================
// prologue: b_ij update + softmax (duplicated x2 across bg blocks sharing a c-range).
__global__ __launch_bounds__(256, 1) void k_gemm1(const float* __restrict__ Xt,
                                                  const float4* __restrict__ Wr4,
                                                  const float* __restrict__ bij_old,
                                                  float* __restrict__ bij_new,
                                                  const float* __restrict__ agg_part,
                                                  float* __restrict__ s_part) {
    __shared__ float braw[720];
    __shared__ float csm[720];
    __shared__ float Ws[72 * 160];
    const int ch = blockIdx.x >> 1, bg = blockIdx.x & 1;
    const int m0 = ch * 72;
    const int c0 = (ch & 15) * 72;        // chunk sits inside one k-slice (1152/72=16)
    const int t = threadIdx.x;

    // ---- b_ij += sum of 32 agg_part slices ; write new buffer ----
    for (int idx = t; idx < 720; idx += 256) {
        float v = bij_old[c0 * J_U + idx];
#pragma unroll
        for (int s = 0; s < 32; ++s) v += agg_part[s * 11520 + c0 * J_U + idx];
        braw[idx] = v;
        bij_new[c0 * J_U + idx] = v;
    }
    __syncthreads();
    for (int idx = t; idx < 720; idx += 256) {    // softmax over j
        const int r0 = (idx / J_U) * J_U;
        float mx = -1e30f;
#pragma unroll
        for (int j = 0; j < J_U; ++j) mx = fmaxf(mx, braw[r0 + j]);
        float sum = 0.f;
#pragma unroll
        for (int j = 0; j < J_U; ++j) sum += __expf(braw[r0 + j] - mx);
        csm[idx] = __expf(braw[idx] - mx) / sum;
    }
    __syncthreads();
    // ---- stage scaled W panel ----
    float4* Ws4 = reinterpret_cast<float4*>(Ws);
    for (int i = t; i < 2880; i += 256) {          // 72 rows x 40 float4
        const int row = i / 40, q = i - row * 40;
        const float sc = csm[row * J_U + (q >> 2)];
        const float4 w = Wr4[(size_t)(m0 + row) * 40 + q];
        Ws4[i] = make_float4(w.x * sc, w.y * sc, w.z * sc, w.w * sc);
    }
    __syncthreads();
    // ---- main loop: x from global (2-deep prefetch), w from LDS (broadcast) ----
    const int bq = t & 15, ng = t >> 4;
    const float* xb = Xt + (size_t)m0 * B_SZ + bg * 128 + bq * 8;
    float acc[8][10] = {};
    float4 a0 = *reinterpret_cast<const float4*>(xb);
    float4 a1 = *reinterpret_cast<const float4*>(xb + 4);
    float4 b0 = *reinterpret_cast<const float4*>(xb + B_SZ);
    float4 b1 = *reinterpret_cast<const float4*>(xb + B_SZ + 4);
#pragma unroll 2
    for (int m = 0; m < 72; ++m) {
        const float* xf = xb + (size_t)(m + 2) * B_SZ;  // rows 9216..9289 hit pad (unused)
        const float4 c0v = *reinterpret_cast<const float4*>(xf);
        const float4 c1v = *reinterpret_cast<const float4*>(xf + 4);
        const float2* wr = reinterpret_cast<const float2*>(Ws + m * N_DIM + ng * J_U);
        const float xv[8] = {a0.x, a0.y, a0.z, a0.w, a1.x, a1.y, a1.z, a1.w};
#pragma unroll
        for (int jj = 0; jj < 5; ++jj) {
            const float2 wv = wr[jj];
#pragma unroll
            for (int i = 0; i < 8; ++i) {
                acc[i][2 * jj]     += xv[i] * wv.x;
                acc[i][2 * jj + 1] += xv[i] * wv.y;
            }
        }
        a0 = b0; a1 = b1; b0 = c0v; b1 = c1v;
    }
    // ---- store split-K partials (plain stores) ----
    float* sp = s_part + (size_t)ch * 40960 + (size_t)(bg * 128 + bq * 8) * N_DIM + ng * J_U;
#pragma unroll
    for (int i = 0; i < 8; ++i) {
        float2* p = reinterpret_cast<float2*>(sp + (size_t)i * N_DIM);
#pragma unroll
        for (int jj = 0; jj < 5; ++jj) p[jj] = make_float2(acc[i][2 * jj], acc[i][2 * jj + 1]);
    }
}

// ================= squash: reduce 128 slices, squash over d -> dst =================
__global__ __launch_bounds__(320) void k_squash(const float* __restrict__ s_part,
                                                float* __restrict__ dst) {
    __shared__ float red[320];
    __shared__ float sq[160];
    const int b = blockIdx.x, t = threadIdx.x;
    const int n = t % 160, h = t / 160;
    float s = 0.f;
    const float* p = s_part + (size_t)h * 64 * 40960 + (size_t)b * N_DIM + n;
#pragma unroll 8
    for (int sl = 0; sl < 64; ++sl) s += p[(size_t)sl * 40960];
    red[t] = s;
    __syncthreads();
    if (t < 160) {
        s = red[t] + red[t + 160] + 1e-5f;   // reference adds 1e-5 BEFORE magnitudes
        sq[t] = s * s;
        red[t] = s;
    }
    __syncthreads();
    if (t < 160) {
        const int j0 = t & ~15;
        float mag = 0.f;
#pragma unroll
        for (int d = 0; d < 16; ++d) mag += sq[j0 + d];
        dst[(size_t)b * N_DIM + t] = red[t] * (sqrtf(mag) / (1.f + mag));
    }
}

// ================= gemm2: 144 m-tiles(64) x 4 b-quarters(64 b) = 576 blocks =========
// G-tile[64][160] = sum_{b in quarter} x[b,m]*v[b,n] in regs (coalesced x reads),
// then LDS round-trip fold with Wr (coalesced float4) -> agg_part[bq*8+k][c][j].
__global__ __launch_bounds__(256) void k_gemm2(const float* __restrict__ x,
                                               const float* __restrict__ v,
                                               const float* __restrict__ Wr,
                                               float* __restrict__ agg_part) {
    __shared__ alignas(16) float VG[64 * 164];   // v-panel [64][160] then G-tile [64][164]
    __shared__ float agg[640];                   // 64 c x 10 j
    const int mt = blockIdx.x >> 2, bq = blockIdx.x & 3;
    const int m0 = mt * 64, b0 = bq * 64;
    const int t = threadIdx.x;
    const int tm = t & 15, ng = t >> 4;

    // stage v quarter (packed [64][160])
    float4* Vs4 = reinterpret_cast<float4*>(VG);
    const float4* v4 = reinterpret_cast<const float4*>(v);
    for (int i = t; i < 2560; i += 256) Vs4[i] = v4[(size_t)bq * 2560 + i];
    for (int i = t; i < 640; i += 256) agg[i] = 0.f;
    __syncthreads();

    // main loop over 64 b: x coalesced (256B/wave-instr), v broadcast from LDS
    float acc[4][10] = {};
    const float* xb = x + (size_t)b0 * M_DIM + m0 + tm * 4;
    const float2* Vs2 = reinterpret_cast<const float2*>(VG);
    float4 p0 = *reinterpret_cast<const float4*>(xb);
    float4 p1 = *reinterpret_cast<const float4*>(xb + M_DIM);
#pragma unroll 2
    for (int b = 0; b < 64; ++b) {
        const int bf = (b + 2 < 64) ? b + 2 : 63;            // clamped prefetch
        const float4 f = *reinterpret_cast<const float4*>(xb + (size_t)bf * M_DIM);
        const float2* vv = Vs2 + b * 80 + ng * 5;
        const float xv[4] = {p0.x, p0.y, p0.z, p0.w};
#pragma unroll
        for (int jj = 0; jj < 5; ++jj) {
            const float2 w = vv[jj];
#pragma unroll
            for (int i = 0; i < 4; ++i) {
                acc[i][2 * jj]     += xv[i] * w.x;
                acc[i][2 * jj + 1] += xv[i] * w.y;
            }
        }
        p0 = p1; p1 = f;
    }
    __syncthreads();   // all waves done reading v-panel; reuse VG for G-tile
    // scatter acc -> G-tile (row stride 164 floats = 656 B, 16B-aligned rows)
#pragma unroll
    for (int i = 0; i < 4; ++i)
#pragma unroll
        for (int q = 0; q < 10; ++q)
            VG[(tm * 4 + i) * 164 + ng * 10 + q] = acc[i][q];
    __syncthreads();
    // coalesced fold: 64 rows x 40 float4 of Wr ⊙ G, one j per float4
    const float4* Wr4 = reinterpret_cast<const float4*>(Wr);
    for (int idx = t; idx < 2560; idx += 256) {
        const int row = idx / 40, q = idx - row * 40;
        const float4 w = Wr4[(size_t)(m0 + row) * 40 + q];
        const float4 g = *reinterpret_cast<const float4*>(&VG[row * 164 + q * 4]);
        atomicAdd(&agg[row * J_U + (q >> 2)], w.x * g.x + w.y * g.y + w.z * g.z + w.w * g.w);
    }
    __syncthreads();
    const int k = m0 / C_IN, c0 = m0 - k * C_IN;   // 64-tile never crosses a k-slice
    for (int i = t; i < 640; i += 256)
        agg_part[(size_t)(bq * 8 + k) * 11520 + c0 * J_U + i] = agg[i];
}

extern "C" void kernel_launch(void* const* d_in, const int* in_sizes, int n_in,
                              void* d_out, int out_size, void* d_ws, size_t ws_size,
                              hipStream_t stream) {
    const float* x = (const float*)d_in[0];   // (256, 8, 1152) fp32
    const float* W = (const float*)d_in[1];   // (1, 1152, 10, 16, 8) fp32
    float* out = (float*)d_out;               // (256, 10, 16, 1) fp32
    float* ws  = (float*)d_ws;
    float* Xt   = ws + OFF_XT;
    float* Wr   = ws + OFF_WR;
    float* sp   = ws + OFF_SP;
    float* v    = ws + OFF_V;
    float* bij0 = ws + OFF_B0;
    float* bij1 = ws + OFF_B1;
    float* agg  = ws + OFF_AG;
    const float4* Wr4 = (const float4*)Wr;

    k_prep<<<2061, 256, 0, stream>>>(x, W, ws);

    for (int it = 0; it < 4; ++it) {
        const float* bo = (it & 1) ? bij1 : bij0;
        float*       bn = (it & 1) ? bij0 : bij1;
        k_gemm1<<<256, 256, 0, stream>>>(Xt, Wr4, bo, bn, agg, sp);
        k_squash<<<256, 320, 0, stream>>>(sp, (it < 3) ? v : out);
        if (it < 3)   // last iteration's agreement is never used
            k_gemm2<<<576, 256, 0, stream>>>(x, v, Wr, agg);
    }
}

// Round 7
// 277.498 us; speedup vs baseline: 1.2751x; 1.0997x over previous
//
#include <hip/hip_runtime.h>

// Capsule routing, factorized, all fp32, multi-kernel (no global atomics).
// B=256, K_IN=8, C=1152, J=10, D=16, 4 iters.
// m = k*1152 + c (M=9216), n = j*16 + d (N=160).
// Per iter: [gemm1] s_part[ch][b][n] = sum_{m in ch} Xt[m,b]*csm[c,j]*Wr[m,n]
//           (gemm1 prologue: b_ij += sum_32 agg_part; csm = softmax(b_ij))
//           [squash] v[b][n] = squash(sum_ch s_part)
//           [gemm2]  G-tile = sum_{b in quarter} x[b,m]*v[b,n] (regs, coalesced x)
//                    then fold with Wr (coalesced, LDS round-trip) -> agg_part[bq*8+k]

#define C_IN  1152
#define J_U   10
#define M_DIM 9216
#define N_DIM 160
#define B_SZ  256

// ---- ws layout (float offsets); ws is 256 MiB so offsets are generous ----
#define OFF_XT   0                    // [9216+4 pad rows][256]
#define OFF_WR   2400000              // [9216][160]
#define OFF_SP   3900000              // [128][256][160]
#define OFF_V    9200000              // [256][160]
#define OFF_B0   9250000              // [1152][10]
#define OFF_B1   9270000              // [1152][10]
#define OFF_AG   9290000              // [32][1152][10]

// ================= prep: transpose x -> Xt, build Wr, zero b_ij/agg =================
__global__ __launch_bounds__(256) void k_prep(const float* __restrict__ x,
                                              const float* __restrict__ W,
                                              float* __restrict__ ws) {
    const int bid = blockIdx.x, t = threadIdx.x;
    if (bid < 576) {                       // 144 m-tiles x 4 b-tiles, 64x64 transpose
        __shared__ float T[64][65];
        const int m0 = (bid % 144) * 64, b0 = (bid / 144) * 64;
        {
            const int b_l = t >> 2, q = t & 3;
            const float* xp = x + (size_t)(b0 + b_l) * M_DIM + m0 + q * 16;
#pragma unroll
            for (int u = 0; u < 4; ++u) {
                const float4 v = *reinterpret_cast<const float4*>(xp + 4 * u);
                T[q * 16 + 4 * u + 0][b_l] = v.x;
                T[q * 16 + 4 * u + 1][b_l] = v.y;
                T[q * 16 + 4 * u + 2][b_l] = v.z;
                T[q * 16 + 4 * u + 3][b_l] = v.w;
            }
        }
        __syncthreads();
        {
            const int m_l = t >> 2, q = t & 3;
            float* Xt = ws + OFF_XT;
            float4* op = reinterpret_cast<float4*>(Xt + (size_t)(m0 + m_l) * B_SZ + b0 + q * 16);
#pragma unroll
            for (int u = 0; u < 4; ++u)
                op[u] = make_float4(T[m_l][q * 16 + 4 * u], T[m_l][q * 16 + 4 * u + 1],
                                    T[m_l][q * 16 + 4 * u + 2], T[m_l][q * 16 + 4 * u + 3]);
        }
    } else if (bid < 2016) {               // Wr[(k*C+c)][n] = W[c][n][k]
        const int i = (bid - 576) * 256 + t;    // [0, 368640)
        const int n = i % N_DIM;
        const int c = (i / N_DIM) % C_IN;
        const int kh = i / (N_DIM * C_IN);      // 0..1
        const float4 w = *reinterpret_cast<const float4*>(W + (size_t)c * 1280 + n * 8 + kh * 4);
        float* Wr = ws + OFF_WR;
        const float wv[4] = {w.x, w.y, w.z, w.w};
#pragma unroll
        for (int j = 0; j < 4; ++j)
            Wr[(size_t)((kh * 4 + j) * C_IN + c) * N_DIM + n] = wv[j];
    } else {                               // zero b_ij (both buffers) + agg_part (32 slices)
        const int idx = (bid - 2016) * 256 + t;   // [0, 11520)
        ws[OFF_B0 + idx] = 0.f;
        ws[OFF_B1 + idx] = 0.f;
#pragma unroll
        for (int s = 0; s < 32; ++s) ws[OFF_AG + s * 11520 + idx] = 0.f;
    }
}

// ================= gemm1: 128 chunks(72 m) x 4 b-quarters(64 b) = 512 blocks =======
// 2 blocks/CU (2 waves/SIMD) + 4-deep x-prefetch to cover post-flush L3 latency.
// prologue: b_ij update + softmax (duplicated x4 across bq blocks sharing a c-range).
__global__ __launch_bounds__(256, 2) void k_gemm1(const float* __restrict__ Xt,
                                                  const float4* __restrict__ Wr4,
                                                  const float* __restrict__ bij_old,
                                                  float* __restrict__ bij_new,
                                                  const float* __restrict__ agg_part,
                                                  float* __restrict__ s_part) {
    __shared__ float braw[720];
    __shared__ float csm[720];
    __shared__ float Ws[72 * 160];
    const int ch = blockIdx.x >> 2, bq4 = blockIdx.x & 3;
    const int m0 = ch * 72;
    const int c0 = (ch & 15) * 72;        // chunk sits inside one k-slice (1152/72=16)
    const int t = threadIdx.x;

    // ---- b_ij += sum of 32 agg_part slices ; write new buffer ----
    for (int idx = t; idx < 720; idx += 256) {
        float v = bij_old[c0 * J_U + idx];
#pragma unroll
        for (int s = 0; s < 32; ++s) v += agg_part[s * 11520 + c0 * J_U + idx];
        braw[idx] = v;
        bij_new[c0 * J_U + idx] = v;
    }
    __syncthreads();
    for (int idx = t; idx < 720; idx += 256) {    // softmax over j
        const int r0 = (idx / J_U) * J_U;
        float mx = -1e30f;
#pragma unroll
        for (int j = 0; j < J_U; ++j) mx = fmaxf(mx, braw[r0 + j]);
        float sum = 0.f;
#pragma unroll
        for (int j = 0; j < J_U; ++j) sum += __expf(braw[r0 + j] - mx);
        csm[idx] = __expf(braw[idx] - mx) / sum;
    }
    __syncthreads();
    // ---- stage scaled W panel ----
    float4* Ws4 = reinterpret_cast<float4*>(Ws);
    for (int i = t; i < 2880; i += 256) {          // 72 rows x 40 float4
        const int row = i / 40, q = i - row * 40;
        const float sc = csm[row * J_U + (q >> 2)];
        const float4 w = Wr4[(size_t)(m0 + row) * 40 + q];
        Ws4[i] = make_float4(w.x * sc, w.y * sc, w.z * sc, w.w * sc);
    }
    __syncthreads();
    // ---- main loop: x from global (4-deep prefetch), w from LDS (broadcast) ----
    const int bq = t & 15, ng = t >> 4;
    const float* xb = Xt + (size_t)m0 * B_SZ + bq4 * 64 + bq * 4;
    float acc[4][10] = {};
    float4 pf[4];
#pragma unroll
    for (int i = 0; i < 4; ++i) pf[i] = *reinterpret_cast<const float4*>(xb + (size_t)i * B_SZ);
#pragma unroll 4
    for (int m = 0; m < 72; ++m) {
        // rows 9216..9219 hit the pad (loaded, never consumed)
        const float4 nxt = *reinterpret_cast<const float4*>(xb + (size_t)(m + 4) * B_SZ);
        const float4 cur = pf[0];
        pf[0] = pf[1]; pf[1] = pf[2]; pf[2] = pf[3]; pf[3] = nxt;
        const float2* wr = reinterpret_cast<const float2*>(Ws + m * N_DIM + ng * J_U);
        const float xv[4] = {cur.x, cur.y, cur.z, cur.w};
#pragma unroll
        for (int jj = 0; jj < 5; ++jj) {
            const float2 wv = wr[jj];
#pragma unroll
            for (int i = 0; i < 4; ++i) {
                acc[i][2 * jj]     += xv[i] * wv.x;
                acc[i][2 * jj + 1] += xv[i] * wv.y;
            }
        }
    }
    // ---- store split-K partials (plain stores) ----
    float* sp = s_part + (size_t)ch * 40960 + (size_t)(bq4 * 64 + bq * 4) * N_DIM + ng * J_U;
#pragma unroll
    for (int i = 0; i < 4; ++i) {
        float2* p = reinterpret_cast<float2*>(sp + (size_t)i * N_DIM);
#pragma unroll
        for (int jj = 0; jj < 5; ++jj) p[jj] = make_float2(acc[i][2 * jj], acc[i][2 * jj + 1]);
    }
}

// ================= squash: reduce 128 slices, squash over d -> dst =================
__global__ __launch_bounds__(320) void k_squash(const float* __restrict__ s_part,
                                                float* __restrict__ dst) {
    __shared__ float red[320];
    __shared__ float sq[160];
    const int b = blockIdx.x, t = threadIdx.x;
    const int n = t % 160, h = t / 160;
    float s = 0.f;
    const float* p = s_part + (size_t)h * 64 * 40960 + (size_t)b * N_DIM + n;
#pragma unroll 8
    for (int sl = 0; sl < 64; ++sl) s += p[(size_t)sl * 40960];
    red[t] = s;
    __syncthreads();
    if (t < 160) {
        s = red[t] + red[t + 160] + 1e-5f;   // reference adds 1e-5 BEFORE magnitudes
        sq[t] = s * s;
        red[t] = s;
    }
    __syncthreads();
    if (t < 160) {
        const int j0 = t & ~15;
        float mag = 0.f;
#pragma unroll
        for (int d = 0; d < 16; ++d) mag += sq[j0 + d];
        dst[(size_t)b * N_DIM + t] = red[t] * (sqrtf(mag) / (1.f + mag));
    }
}

// ================= gemm2: 144 m-tiles(64) x 4 b-quarters(64 b) = 576 blocks =========
// G-tile[64][160] = sum_{b in quarter} x[b,m]*v[b,n] in regs (coalesced x, 4-deep pf),
// then LDS round-trip fold with Wr (coalesced float4) -> agg_part[bq*8+k][c][j].
__global__ __launch_bounds__(256) void k_gemm2(const float* __restrict__ x,
                                               const float* __restrict__ v,
                                               const float* __restrict__ Wr,
                                               float* __restrict__ agg_part) {
    __shared__ alignas(16) float VG[64 * 164];   // v-panel [64][160] then G-tile [64][164]
    __shared__ float agg[640];                   // 64 c x 10 j
    const int mt = blockIdx.x >> 2, bq = blockIdx.x & 3;
    const int m0 = mt * 64, b0 = bq * 64;
    const int t = threadIdx.x;
    const int tm = t & 15, ng = t >> 4;

    // stage v quarter (packed [64][160])
    float4* Vs4 = reinterpret_cast<float4*>(VG);
    const float4* v4 = reinterpret_cast<const float4*>(v);
    for (int i = t; i < 2560; i += 256) Vs4[i] = v4[(size_t)bq * 2560 + i];
    for (int i = t; i < 640; i += 256) agg[i] = 0.f;
    __syncthreads();

    // main loop over 64 b: x coalesced (256B/wave-instr), v broadcast from LDS
    float acc[4][10] = {};
    const float* xb = x + (size_t)b0 * M_DIM + m0 + tm * 4;
    const float2* Vs2 = reinterpret_cast<const float2*>(VG);
    float4 pf[4];
#pragma unroll
    for (int i = 0; i < 4; ++i) pf[i] = *reinterpret_cast<const float4*>(xb + (size_t)i * M_DIM);
#pragma unroll 4
    for (int b = 0; b < 64; ++b) {
        const int bf = (b + 4 < 64) ? b + 4 : 63;            // clamped prefetch
        const float4 nxt = *reinterpret_cast<const float4*>(xb + (size_t)bf * M_DIM);
        const float4 cur = pf[0];
        pf[0] = pf[1]; pf[1] = pf[2]; pf[2] = pf[3]; pf[3] = nxt;
        const float2* vv = Vs2 + b * 80 + ng * 5;
        const float xv[4] = {cur.x, cur.y, cur.z, cur.w};
#pragma unroll
        for (int jj = 0; jj < 5; ++jj) {
            const float2 w = vv[jj];
#pragma unroll
            for (int i = 0; i < 4; ++i) {
                acc[i][2 * jj]     += xv[i] * w.x;
                acc[i][2 * jj + 1] += xv[i] * w.y;
            }
        }
    }
    __syncthreads();   // all waves done reading v-panel; reuse VG for G-tile
    // scatter acc -> G-tile (row stride 164 floats = 656 B, 16B-aligned rows)
#pragma unroll
    for (int i = 0; i < 4; ++i)
#pragma unroll
        for (int q = 0; q < 10; ++q)
            VG[(tm * 4 + i) * 164 + ng * 10 + q] = acc[i][q];
    __syncthreads();
    // coalesced fold: 64 rows x 40 float4 of Wr ⊙ G, one j per float4
    const float4* Wr4 = reinterpret_cast<const float4*>(Wr);
    for (int idx = t; idx < 2560; idx += 256) {
        const int row = idx / 40, q = idx - row * 40;
        const float4 w = Wr4[(size_t)(m0 + row) * 40 + q];
        const float4 g = *reinterpret_cast<const float4*>(&VG[row * 164 + q * 4]);
        atomicAdd(&agg[row * J_U + (q >> 2)], w.x * g.x + w.y * g.y + w.z * g.z + w.w * g.w);
    }
    __syncthreads();
    const int k = m0 / C_IN, c0 = m0 - k * C_IN;   // 64-tile never crosses a k-slice
    for (int i = t; i < 640; i += 256)
        agg_part[(size_t)(bq * 8 + k) * 11520 + c0 * J_U + i] = agg[i];
}

extern "C" void kernel_launch(void* const* d_in, const int* in_sizes, int n_in,
                              void* d_out, int out_size, void* d_ws, size_t ws_size,
                              hipStream_t stream) {
    const float* x = (const float*)d_in[0];   // (256, 8, 1152) fp32
    const float* W = (const float*)d_in[1];   // (1, 1152, 10, 16, 8) fp32
    float* out = (float*)d_out;               // (256, 10, 16, 1) fp32
    float* ws  = (float*)d_ws;
    float* Xt   = ws + OFF_XT;
    float* Wr   = ws + OFF_WR;
    float* sp   = ws + OFF_SP;
    float* v    = ws + OFF_V;
    float* bij0 = ws + OFF_B0;
    float* bij1 = ws + OFF_B1;
    float* agg  = ws + OFF_AG;
    const float4* Wr4 = (const float4*)Wr;

    k_prep<<<2061, 256, 0, stream>>>(x, W, ws);

    for (int it = 0; it < 4; ++it) {
        const float* bo = (it & 1) ? bij1 : bij0;
        float*       bn = (it & 1) ? bij0 : bij1;
        k_gemm1<<<512, 256, 0, stream>>>(Xt, Wr4, bo, bn, agg, sp);
        k_squash<<<256, 320, 0, stream>>>(sp, (it < 3) ? v : out);
        if (it < 3)   // last iteration's agreement is never used
            k_gemm2<<<576, 256, 0, stream>>>(x, v, Wr, agg);
    }
}